// Round 1
// baseline (2194.985 us; speedup 1.0000x reference)
//
#include <hip/hip_runtime.h>
#include <math.h>

#define EPSF 1e-8f
#define LR   1e-3f

#define HH 512
#define KK 64
#define SS 4      // samples per block
#define TH 128    // h-tile
#define NT 4      // HH/TH
#define GH 52     // padded per-h stride (floats) in g buffer: 4*12 + 4

__device__ __forceinline__ float rdlane(float v, int l) {
  return __int_as_float(__builtin_amdgcn_readlane(__float_as_int(v), l));
}

// ws layout (floats):
//   BTz  @ 0      : [(k*512 + h)*4 + m]   (131072 floats)
//   Bz   @ 131072 : [(h*64 + k)*4 + m]    (131072 floats)
//   BpT  @ 262144 : [h*64 + k] = Bp[k*512+h]  (32768 floats)
__global__ void prep_kernel(const float* __restrict__ B,
                            const float* __restrict__ Bd,
                            const float* __restrict__ Bdd,
                            const float* __restrict__ Bddd,
                            const float* __restrict__ Bp,
                            float* __restrict__ ws) {
  int tid = blockIdx.x * 256 + threadIdx.x;
  if (tid < 32768) {
    int k = tid >> 9, h = tid & 511;
    int src = h * 64 + k;
    float4 v = make_float4(B[src], Bd[src], Bdd[src], Bddd[src]);
    ((float4*)ws)[tid] = v;
  } else if (tid < 65536) {
    int i = tid - 32768;
    float4 v = make_float4(B[i], Bd[i], Bdd[i], Bddd[i]);
    ((float4*)(ws + 131072))[i] = v;
  } else if (tid < 98304) {
    int i = tid - 65536;
    int h = i >> 6, k = i & 63;
    ws[262144 + i] = Bp[k * 512 + h];
  }
}

__global__ __launch_bounds__(256, 4)
void copt_kernel(const float* __restrict__ R_U,
                 const float* __restrict__ alpha,
                 const float* __restrict__ beta,
                 const float* __restrict__ lambdas,
                 const float* __restrict__ ws,
                 float* __restrict__ out) {
  __shared__ __align__(16) float Cl[SS][KK][4];   // C, c-dim padded to 4
  __shared__ __align__(16) float G[TH * GH];      // g[h_l*GH + s*12 + j]

  const float4* BTz = (const float4*)ws;
  const float4* Bz  = (const float4*)(ws + 131072);
  const float*  BpT = ws + 262144;

  const int tid  = threadIdx.x;
  const int lane = tid & 63;
  const int wid  = tid >> 6;

  const float l1 = lambdas[0], l2 = lambdas[1], l3 = lambdas[2];

  // ---------------- C0: thread (k=lane, s=wid) ----------------
  {
    const int s  = wid;
    const int sg = blockIdx.x * SS + s;
    const float* rs = R_U + (size_t)sg * (HH * 3);
    float c0 = 0.f, c1 = 0.f, c2 = 0.f;
    const float* bp = BpT + lane;
    for (int h = 0; h < HH; ++h) {
      float b = bp[h * 64];                 // coalesced over lanes
      const float* rp = rs + h * 3;         // wave-uniform
      c0 = fmaf(b, rp[0], c0);
      c1 = fmaf(b, rp[1], c1);
      c2 = fmaf(b, rp[2], c2);
    }
    Cl[s][lane][0] = c0; Cl[s][lane][1] = c1;
    Cl[s][lane][2] = c2; Cl[s][lane][3] = 0.f;
  }
  __syncthreads();

  // pass1 ids: thread owns one h-row (h_l), two samples (s0,s1)
  const int h_l = tid & 127;
  const int sh  = tid >> 7;                 // 0/1
  const int s0 = 2 * sh, s1 = s0 + 1;
  const int sg0 = blockIdx.x * SS + s0;
  const int sg1 = sg0 + 1;
  const float a0 = alpha[sg0], a1 = alpha[sg1];
  const float b0 = beta[sg0],  b1 = beta[sg1];
  const float* r0base = R_U + (size_t)sg0 * (HH * 3);
  const float* r1base = R_U + (size_t)sg1 * (HH * 3);

  // pass2 ids: (k=lane, s=wid)
  const int ps  = wid;
  const int psg = blockIdx.x * SS + ps;

  // elementwise gradient (matches JAX autodiff incl. clip gates)
  auto elem = [&](const float acc[12], float aa, float bb,
                  const float* rp, float* gp) {
    float P0=acc[0],P1=acc[1],P2=acc[2];
    float V0=acc[3],V1=acc[4],V2=acc[5];
    float A0=acc[6],A1=acc[7],A2=acc[8];
    float J0=acc[9],J1=acc[10],J2=acc[11];
    float v2 = V0*V0 + V1*V1 + V2*V2;
    float v  = sqrtf(v2);
    float ve = v + EPSF;
    float cx0 = V1*A2 - V2*A1;
    float cx1 = V2*A0 - V0*A2;
    float cx2 = V0*A1 - V1*A0;
    float nc  = sqrtf(cx0*cx0 + cx1*cx1 + cx2*cx2);
    float ve2 = ve*ve;
    float denom = ve2*ve + EPSF;
    float invd  = 1.f/denom;
    float kappa = nc * invd;
    float ks  = fminf(fmaxf(kappa, 1e-4f), 1e4f);
    float lpr = bb * logf(ks);
    float lp  = fminf(fmaxf(lpr, -10.f), 10.f);
    float tr  = aa * expf(lp);
    float tt  = fminf(fmaxf(tr, 1e-6f), 1e6f);
    float s2  = 2.f*l2*(v - tt);
    float gtr  = (tr > 1e-6f && tr < 1e6f) ? -s2 : 0.f;
    float glpr = (lpr > -10.f && lpr < 10.f) ? gtr*tr : 0.f;
    float gk   = (kappa > 1e-4f && kappa < 1e4f) ? glpr*bb/ks : 0.f;
    float gnc  = gk * invd;
    float gden = -gk * kappa * invd;
    float gve  = 3.f * ve2 * gden;
    float gv   = s2 + gve;
    float giv  = gv / v;
    float gcs  = gnc / nc;
    float gc0 = gcs*cx0, gc1 = gcs*cx1, gc2 = gcs*cx2;
    gp[0]  = 2.f*l1*(P0 - rp[0]);
    gp[1]  = 2.f*l1*(P1 - rp[1]);
    gp[2]  = 2.f*l1*(P2 - rp[2]);
    gp[3]  = fmaf(giv, V0, A1*gc2 - A2*gc1);
    gp[4]  = fmaf(giv, V1, A2*gc0 - A0*gc2);
    gp[5]  = fmaf(giv, V2, A0*gc1 - A1*gc0);
    gp[6]  = gc1*V2 - gc2*V1;
    gp[7]  = gc2*V0 - gc0*V2;
    gp[8]  = gc0*V1 - gc1*V0;
    gp[9]  = 2.f*l3*J0;
    gp[10] = 2.f*l3*J1;
    gp[11] = 2.f*l3*J2;
  };

  float ga0 = 0.f, ga1 = 0.f, ga2 = 0.f;

  for (int it = 0; it < 3; ++it) {
    ga0 = ga1 = ga2 = 0.f;
    for (int t = 0; t < NT; ++t) {
      const int h0 = t * TH;

      // ---------------- pass1: forward + elementwise ----------------
      float acc0[12], acc1[12];
      #pragma unroll
      for (int j = 0; j < 12; ++j) { acc0[j] = 0.f; acc1[j] = 0.f; }
      {
        const float4* bt = BTz + (h0 + h_l);
        #pragma unroll 4
        for (int k = 0; k < KK; ++k) {
          float4 bq = bt[k * 512];                       // coalesced b128
          float4 cA = *(const float4*)&Cl[s0][k][0];     // LDS broadcast
          float4 cB = *(const float4*)&Cl[s1][k][0];
          acc0[0] = fmaf(bq.x, cA.x, acc0[0]);
          acc0[1] = fmaf(bq.x, cA.y, acc0[1]);
          acc0[2] = fmaf(bq.x, cA.z, acc0[2]);
          acc0[3] = fmaf(bq.y, cA.x, acc0[3]);
          acc0[4] = fmaf(bq.y, cA.y, acc0[4]);
          acc0[5] = fmaf(bq.y, cA.z, acc0[5]);
          acc0[6] = fmaf(bq.z, cA.x, acc0[6]);
          acc0[7] = fmaf(bq.z, cA.y, acc0[7]);
          acc0[8] = fmaf(bq.z, cA.z, acc0[8]);
          acc0[9] = fmaf(bq.w, cA.x, acc0[9]);
          acc0[10]= fmaf(bq.w, cA.y, acc0[10]);
          acc0[11]= fmaf(bq.w, cA.z, acc0[11]);
          acc1[0] = fmaf(bq.x, cB.x, acc1[0]);
          acc1[1] = fmaf(bq.x, cB.y, acc1[1]);
          acc1[2] = fmaf(bq.x, cB.z, acc1[2]);
          acc1[3] = fmaf(bq.y, cB.x, acc1[3]);
          acc1[4] = fmaf(bq.y, cB.y, acc1[4]);
          acc1[5] = fmaf(bq.y, cB.z, acc1[5]);
          acc1[6] = fmaf(bq.z, cB.x, acc1[6]);
          acc1[7] = fmaf(bq.z, cB.y, acc1[7]);
          acc1[8] = fmaf(bq.z, cB.z, acc1[8]);
          acc1[9] = fmaf(bq.w, cB.x, acc1[9]);
          acc1[10]= fmaf(bq.w, cB.y, acc1[10]);
          acc1[11]= fmaf(bq.w, cB.z, acc1[11]);
        }
      }
      {
        const int h = h0 + h_l;
        elem(acc0, a0, b0, r0base + (size_t)h * 3, &G[h_l * GH + s0 * 12]);
        elem(acc1, a1, b1, r1base + (size_t)h * 3, &G[h_l * GH + s1 * 12]);
      }
      __syncthreads();

      // ---------------- pass2: backward accumulate ----------------
      {
        const float4* bz = Bz + (h0 * 64 + lane);
        const int gidx = ((lane & 15) < 12) ? (lane & 15) : 0;
        #pragma unroll 2
        for (int hl = 0; hl < TH; ++hl) {
          float gval = G[hl * GH + ps * 12 + gidx];  // 12 distinct words, rest dup
          float4 bq = bz[hl * 64];                   // coalesced b128, 4 matrices
          float g0 = rdlane(gval, 0),  g1 = rdlane(gval, 1),  g2  = rdlane(gval, 2);
          float g3 = rdlane(gval, 3),  g4 = rdlane(gval, 4),  g5  = rdlane(gval, 5);
          float g6 = rdlane(gval, 6),  g7 = rdlane(gval, 7),  g8  = rdlane(gval, 8);
          float g9 = rdlane(gval, 9),  g10= rdlane(gval, 10), g11 = rdlane(gval, 11);
          ga0 = fmaf(bq.x, g0, fmaf(bq.y, g3, fmaf(bq.z, g6, fmaf(bq.w, g9,  ga0))));
          ga1 = fmaf(bq.x, g1, fmaf(bq.y, g4, fmaf(bq.z, g7, fmaf(bq.w, g10, ga1))));
          ga2 = fmaf(bq.x, g2, fmaf(bq.y, g5, fmaf(bq.z, g8, fmaf(bq.w, g11, ga2))));
        }
      }
      __syncthreads();
    }
    // gradient step: thread (k=lane, s=wid) owns C[s][k][*]
    Cl[ps][lane][0] -= LR * ga0;
    Cl[ps][lane][1] -= LR * ga1;
    Cl[ps][lane][2] -= LR * ga2;
    __syncthreads();
  }

  float* op = out + ((size_t)psg * KK + lane) * 3;
  op[0] = Cl[ps][lane][0];
  op[1] = Cl[ps][lane][1];
  op[2] = Cl[ps][lane][2];
}

extern "C" void kernel_launch(void* const* d_in, const int* in_sizes, int n_in,
                              void* d_out, int out_size, void* d_ws, size_t ws_size,
                              hipStream_t stream) {
  const float* R_U     = (const float*)d_in[0];
  const float* alpha   = (const float*)d_in[1];
  const float* beta    = (const float*)d_in[2];
  const float* lambdas = (const float*)d_in[3];
  const float* B       = (const float*)d_in[4];
  const float* Bd      = (const float*)d_in[5];
  const float* Bdd     = (const float*)d_in[6];
  const float* Bddd    = (const float*)d_in[7];
  const float* Bp      = (const float*)d_in[8];
  float* ws = (float*)d_ws;
  const int nB = in_sizes[1];   // 16384 samples

  hipLaunchKernelGGL(prep_kernel, dim3(384), dim3(256), 0, stream,
                     B, Bd, Bdd, Bddd, Bp, ws);
  hipLaunchKernelGGL(copt_kernel, dim3(nB / SS), dim3(256), 0, stream,
                     R_U, alpha, beta, lambdas, ws, (float*)d_out);
}

// Round 2
// 1352.819 us; speedup vs baseline: 1.6225x; 1.6225x over previous
//
#include <hip/hip_runtime.h>
#include <math.h>

#define EPSF 1e-8f
#define LR   1e-3f

#define HH 512
#define KK 64
#define SS 4      // samples per block
#define TH 128    // h-tile (chunk)
#define NT 4      // HH/TH
#define GST 520   // Gb col stride in bf16 elems (16B-aligned: 520*2=1040)

typedef short  bf16x8 __attribute__((ext_vector_type(8)));
typedef float  f32x4  __attribute__((ext_vector_type(4)));

__device__ __forceinline__ unsigned short f2bf(float x) {
  unsigned int u = __float_as_uint(x);
  return (unsigned short)((u + 0x7fffu + ((u >> 16) & 1u)) >> 16);
}
__device__ __forceinline__ float bfhi(float x) {   // bf16-rounded value of x
  return __uint_as_float(((unsigned int)f2bf(x)) << 16);
}

// ws layout (float units):
//   BTz @ 0      : [(k*512 + h)*4 + m]  forward-packed 4 matrices (131072 f)
//   BpT @ 131072 : [h*64 + k] = Bp[k*512+h]                        (32768 f)
//   AF  @ 163840 : backward A-fragments, hi/lo bf16 (262144 ushorts = 512KB)
//     frag idx f = ((chunk*16 + kstep)*4 + mtile)*2 + hilo; elem = f*512 + lane*8 + j
//     value: khat = mtile*16 + (lane&15); Kl = kstep*32 + (lane>>4)*8 + j;
//            z = Kl>>7; h = chunk*128 + (Kl&127); val = Mz[h*64 + khat]
__global__ void prep_kernel(const float* __restrict__ B,
                            const float* __restrict__ Bd,
                            const float* __restrict__ Bdd,
                            const float* __restrict__ Bddd,
                            const float* __restrict__ Bp,
                            float* __restrict__ ws) {
  int tid = blockIdx.x * 256 + threadIdx.x;   // 512 blocks * 256 = 131072
  if (tid < 32768) {
    int k = tid >> 9, h = tid & 511;
    int src = h * 64 + k;
    ((float4*)ws)[tid] = make_float4(B[src], Bd[src], Bdd[src], Bddd[src]);
  } else if (tid < 65536) {
    int i = tid - 32768;
    int h = i >> 6, k = i & 63;
    ws[131072 + i] = Bp[k * 512 + h];
  }
  // backward A-fragments: each thread packs 2 bf16 into one uint
  {
    const float* Ms[4] = {B, Bd, Bdd, Bddd};
    unsigned int idx = 2u * (unsigned)tid;       // even
    unsigned int out;
    unsigned short bits[2];
    #pragma unroll
    for (int t = 0; t < 2; ++t) {
      unsigned int id = idx + t;
      int j     = id & 7;
      int lane  = (id >> 3) & 63;
      int hilo  = (id >> 9) & 1;
      int mtile = (id >> 10) & 3;
      int kstep = (id >> 12) & 15;
      int chunk = (id >> 16) & 3;
      int khat = mtile * 16 + (lane & 15);
      int Kl   = kstep * 32 + ((lane >> 4) << 3) + j;
      int z    = Kl >> 7;
      int h    = chunk * 128 + (Kl & 127);
      float val = Ms[z][h * 64 + khat];
      float hi = bfhi(val);
      bits[t] = hilo ? f2bf(val - hi) : f2bf(hi);
    }
    out = ((unsigned int)bits[1] << 16) | (unsigned int)bits[0];
    ((unsigned int*)(ws + 163840))[tid] = out;
  }
}

__global__ __launch_bounds__(256, 4)
void copt_kernel(const float* __restrict__ R_U,
                 const float* __restrict__ alpha,
                 const float* __restrict__ beta,
                 const float* __restrict__ lambdas,
                 const float* __restrict__ ws,
                 float* __restrict__ out) {
  __shared__ __align__(16) float Cl[SS][KK][4];         // 4 KB
  __shared__ __align__(16) unsigned short Gb[16 * GST]; // 16.6 KB bf16 g-operand

  const float4* BTz = (const float4*)ws;
  const float*  BpT = ws + 131072;
  const unsigned short* AF = (const unsigned short*)(ws + 163840);

  const int tid  = threadIdx.x;
  const int lane = tid & 63;
  const int wid  = tid >> 6;

  const float l1 = lambdas[0], l2 = lambdas[1], l3 = lambdas[2];

  // zero Gb (cols 12..15 must be zero; rest overwritten per chunk)
  for (int i = tid; i < (16 * GST) / 2; i += 256) ((unsigned int*)Gb)[i] = 0u;

  // ---------------- C0: thread (k=lane, s=wid) ----------------
  {
    const int s  = wid;
    const int sg = blockIdx.x * SS + s;
    const float* rs = R_U + (size_t)sg * (HH * 3);
    float c0 = 0.f, c1 = 0.f, c2 = 0.f;
    const float* bp = BpT + lane;
    for (int h = 0; h < HH; ++h) {
      float b = bp[h * 64];                 // coalesced over lanes
      const float* rp = rs + h * 3;         // wave-uniform
      c0 = fmaf(b, rp[0], c0);
      c1 = fmaf(b, rp[1], c1);
      c2 = fmaf(b, rp[2], c2);
    }
    Cl[s][lane][0] = c0; Cl[s][lane][1] = c1;
    Cl[s][lane][2] = c2; Cl[s][lane][3] = 0.f;
  }
  __syncthreads();

  // pass1 ids: thread owns one h-row (h_l), two samples (s0,s1)
  const int h_l = tid & 127;
  const int sh  = tid >> 7;                 // 0/1
  const int s0 = 2 * sh, s1 = s0 + 1;
  const int sg0 = blockIdx.x * SS + s0;
  const int sg1 = sg0 + 1;
  const float a0 = alpha[sg0], a1 = alpha[sg1];
  const float b0 = beta[sg0],  b1 = beta[sg1];
  const float* r0base = R_U + (size_t)sg0 * (HH * 3);
  const float* r1base = R_U + (size_t)sg1 * (HH * 3);

  // output ids: (k=lane, s=wid)
  const int ps  = wid;
  const int psg = blockIdx.x * SS + ps;

  // elementwise gradient (JAX autodiff semantics, fast-math hw intrinsics)
  auto elem = [&](const float acc[12], float aa, float bb,
                  const float* rp, float g[12]) {
    float P0=acc[0],P1=acc[1],P2=acc[2];
    float V0=acc[3],V1=acc[4],V2=acc[5];
    float A0=acc[6],A1=acc[7],A2=acc[8];
    float J0=acc[9],J1=acc[10],J2=acc[11];
    float v2 = V0*V0 + V1*V1 + V2*V2;
    float v  = __builtin_amdgcn_sqrtf(v2);
    float ve = v + EPSF;
    float cx0 = V1*A2 - V2*A1;
    float cx1 = V2*A0 - V0*A2;
    float cx2 = V0*A1 - V1*A0;
    float nc  = __builtin_amdgcn_sqrtf(cx0*cx0 + cx1*cx1 + cx2*cx2);
    float ve2 = ve*ve;
    float denom = ve2*ve + EPSF;
    float invd  = __builtin_amdgcn_rcpf(denom);
    float kappa = nc * invd;
    float ks  = fminf(fmaxf(kappa, 1e-4f), 1e4f);
    float lpr = bb * __logf(ks);
    float lp  = fminf(fmaxf(lpr, -10.f), 10.f);
    float tr  = aa * __expf(lp);
    float tt  = fminf(fmaxf(tr, 1e-6f), 1e6f);
    float s2  = 2.f*l2*(v - tt);
    float gtr  = (tr > 1e-6f && tr < 1e6f) ? -s2 : 0.f;
    float glpr = (lpr > -10.f && lpr < 10.f) ? gtr*tr : 0.f;
    float gk   = (kappa > 1e-4f && kappa < 1e4f)
                   ? glpr*bb*__builtin_amdgcn_rcpf(ks) : 0.f;
    float gnc  = gk * invd;
    float gden = -gk * kappa * invd;
    float gve  = 3.f * ve2 * gden;
    float gv   = s2 + gve;
    float giv  = gv * __builtin_amdgcn_rcpf(v);
    float gcs  = gnc * __builtin_amdgcn_rcpf(nc);
    float gc0 = gcs*cx0, gc1 = gcs*cx1, gc2 = gcs*cx2;
    g[0]  = 2.f*l1*(P0 - rp[0]);
    g[1]  = 2.f*l1*(P1 - rp[1]);
    g[2]  = 2.f*l1*(P2 - rp[2]);
    g[3]  = fmaf(giv, V0, A1*gc2 - A2*gc1);
    g[4]  = fmaf(giv, V1, A2*gc0 - A0*gc2);
    g[5]  = fmaf(giv, V2, A0*gc1 - A1*gc0);
    g[6]  = gc1*V2 - gc2*V1;
    g[7]  = gc2*V0 - gc0*V2;
    g[8]  = gc0*V1 - gc1*V0;
    g[9]  = 2.f*l3*J0;
    g[10] = 2.f*l3*J1;
    g[11] = 2.f*l3*J2;
  };

  for (int it = 0; it < 3; ++it) {
    f32x4 gacc = {0.f, 0.f, 0.f, 0.f};       // backward MFMA accumulator

    for (int t = 0; t < NT; ++t) {
      const int h0 = t * TH;

      // ---------------- pass1: forward + elementwise (fp32) ----------------
      float acc0[12], acc1[12];
      #pragma unroll
      for (int j = 0; j < 12; ++j) { acc0[j] = 0.f; acc1[j] = 0.f; }
      {
        const float4* bt = BTz + (h0 + h_l);
        #pragma unroll 4
        for (int k = 0; k < KK; ++k) {
          float4 bq = bt[k * 512];                       // coalesced b128
          float4 cA = *(const float4*)&Cl[s0][k][0];     // LDS broadcast
          float4 cB = *(const float4*)&Cl[s1][k][0];
          acc0[0] = fmaf(bq.x, cA.x, acc0[0]);
          acc0[1] = fmaf(bq.x, cA.y, acc0[1]);
          acc0[2] = fmaf(bq.x, cA.z, acc0[2]);
          acc0[3] = fmaf(bq.y, cA.x, acc0[3]);
          acc0[4] = fmaf(bq.y, cA.y, acc0[4]);
          acc0[5] = fmaf(bq.y, cA.z, acc0[5]);
          acc0[6] = fmaf(bq.z, cA.x, acc0[6]);
          acc0[7] = fmaf(bq.z, cA.y, acc0[7]);
          acc0[8] = fmaf(bq.z, cA.z, acc0[8]);
          acc0[9] = fmaf(bq.w, cA.x, acc0[9]);
          acc0[10]= fmaf(bq.w, cA.y, acc0[10]);
          acc0[11]= fmaf(bq.w, cA.z, acc0[11]);
          acc1[0] = fmaf(bq.x, cB.x, acc1[0]);
          acc1[1] = fmaf(bq.x, cB.y, acc1[1]);
          acc1[2] = fmaf(bq.x, cB.z, acc1[2]);
          acc1[3] = fmaf(bq.y, cB.x, acc1[3]);
          acc1[4] = fmaf(bq.y, cB.y, acc1[4]);
          acc1[5] = fmaf(bq.y, cB.z, acc1[5]);
          acc1[6] = fmaf(bq.z, cB.x, acc1[6]);
          acc1[7] = fmaf(bq.z, cB.y, acc1[7]);
          acc1[8] = fmaf(bq.z, cB.z, acc1[8]);
          acc1[9] = fmaf(bq.w, cB.x, acc1[9]);
          acc1[10]= fmaf(bq.w, cB.y, acc1[10]);
          acc1[11]= fmaf(bq.w, cB.z, acc1[11]);
        }
      }
      {
        const int h = h0 + h_l;
        float g0[12], g1[12];
        elem(acc0, a0, b0, r0base + (size_t)h * 3, g0);
        elem(acc1, a1, b1, r1base + (size_t)h * 3, g1);
        // store g as bf16 into Gb[col=3s+m][K = z*128 + h_l]
        #pragma unroll
        for (int z = 0; z < 4; ++z) {
          #pragma unroll
          for (int m = 0; m < 3; ++m) {
            Gb[(3*s0 + m) * GST + z*128 + h_l] = f2bf(g0[z*3 + m]);
            Gb[(3*s1 + m) * GST + z*128 + h_l] = f2bf(g1[z*3 + m]);
          }
        }
      }
      __syncthreads();

      // ---------------- pass2: backward via MFMA ----------------
      // grad_C (64 x 12) += BT4 (64 x 512-chunk) @ g (512-chunk x 12)
      // A = prepacked hi/lo bf16 frags (this wave's 16-row m-tile = wid)
      {
        const int quad = lane >> 4;
        const unsigned short* gbase = &Gb[(lane & 15) * GST + quad * 8];
        #pragma unroll 4
        for (int ks = 0; ks < 16; ++ks) {
          const unsigned short* pA =
              AF + (size_t)((((t * 16 + ks) * 4 + wid) * 2) * 512 + lane * 8);
          bf16x8 ah = *(const bf16x8*)pA;
          bf16x8 al = *(const bf16x8*)(pA + 512);
          bf16x8 gg = *(const bf16x8*)(gbase + ks * 32);
          gacc = __builtin_amdgcn_mfma_f32_16x16x32_bf16(ah, gg, gacc, 0, 0, 0);
          gacc = __builtin_amdgcn_mfma_f32_16x16x32_bf16(al, gg, gacc, 0, 0, 0);
        }
      }
      __syncthreads();
    }

    // gradient step from MFMA D-layout: col=lane&15 -> (s,m), row=quad*4+reg
    {
      const int c = lane & 15;
      if (c < 12) {
        const int s = (c * 86) >> 8;        // c/3
        const int m = c - 3 * s;
        const int kr = wid * 16 + ((lane >> 4) << 2);
        Cl[s][kr + 0][m] -= LR * gacc[0];
        Cl[s][kr + 1][m] -= LR * gacc[1];
        Cl[s][kr + 2][m] -= LR * gacc[2];
        Cl[s][kr + 3][m] -= LR * gacc[3];
      }
    }
    __syncthreads();
  }

  float* op = out + ((size_t)psg * KK + lane) * 3;
  op[0] = Cl[ps][lane][0];
  op[1] = Cl[ps][lane][1];
  op[2] = Cl[ps][lane][2];
}

extern "C" void kernel_launch(void* const* d_in, const int* in_sizes, int n_in,
                              void* d_out, int out_size, void* d_ws, size_t ws_size,
                              hipStream_t stream) {
  const float* R_U     = (const float*)d_in[0];
  const float* alpha   = (const float*)d_in[1];
  const float* beta    = (const float*)d_in[2];
  const float* lambdas = (const float*)d_in[3];
  const float* B       = (const float*)d_in[4];
  const float* Bd      = (const float*)d_in[5];
  const float* Bdd     = (const float*)d_in[6];
  const float* Bddd    = (const float*)d_in[7];
  const float* Bp      = (const float*)d_in[8];
  float* ws = (float*)d_ws;
  const int nB = in_sizes[1];   // 16384 samples

  hipLaunchKernelGGL(prep_kernel, dim3(512), dim3(256), 0, stream,
                     B, Bd, Bdd, Bddd, Bp, ws);
  hipLaunchKernelGGL(copt_kernel, dim3(nB / SS), dim3(256), 0, stream,
                     R_U, alpha, beta, lambdas, ws, (float*)d_out);
}

// Round 3
// 545.344 us; speedup vs baseline: 4.0250x; 2.4807x over previous
//
#include <hip/hip_runtime.h>
#include <math.h>

#define EPSF 1e-8f
#define LR   1e-3f

#define HH 512
#define KK 64
#define SS 4       // samples per block
#define TH 128     // h-tile (chunk)
#define NT 4       // HH/TH
#define GST 520    // Gb col stride (ush), 16B-aligned
#define PST 53     // Pb row stride (dwords): 4*13+1, odd -> spreads banks

typedef short    bf16x8 __attribute__((ext_vector_type(8)));
typedef _Float16 f16x8  __attribute__((ext_vector_type(8)));
typedef float    f32x4  __attribute__((ext_vector_type(4)));

__device__ __forceinline__ unsigned short f2bf(float x) {
  unsigned int u = __float_as_uint(x);
  return (unsigned short)((u + 0x7fffu + ((u >> 16) & 1u)) >> 16);
}
__device__ __forceinline__ float bfhi(float x) {
  return __uint_as_float(((unsigned int)f2bf(x)) << 16);
}
__device__ __forceinline__ unsigned short f2h(float x) {
  _Float16 h = (_Float16)x;
  return *(unsigned short*)&h;
}

// ws layout (ushort units):
//  AFb @ 0      (262144): bwd A-frags bf16 hi/lo
//     f=((chunk*16+ks)*4+mt)*2+hilo; elem=f*512+lane*8+j
//     khat=mt*16+(lane&15); Kl=ks*32+(lane>>4)*8+j; z=Kl>>7; h=chunk*128+(Kl&127); val=Mz[h*64+khat]
//  AFf @ 262144 (131072): fwd A-frags fp16 single
//     f=((z*32+ht)*2+kap); elem=f*512+lane*8+j
//     h=ht*16+(lane&15); kk=kap*32+(lane>>4)*8+j; val=Mz[h*64+kk]
//  AFp @ 393216 (65536):  C0 A-frags bf16 hi/lo (Bp)
//     f=(ks*4+mt)*2+hilo; elem=f*512+lane*8+j
//     khat=mt*16+(lane&15); Kl=ks*32+(lane>>4)*8+j; val=Bp[khat*512+Kl]
__global__ void prep_kernel(const float* __restrict__ B,
                            const float* __restrict__ Bd,
                            const float* __restrict__ Bdd,
                            const float* __restrict__ Bddd,
                            const float* __restrict__ Bp,
                            unsigned short* __restrict__ ws) {
  int tid = blockIdx.x * 256 + threadIdx.x;   // 896*256 = 229376
  const float* Ms[4] = {B, Bd, Bdd, Bddd};
  unsigned short bits[2];
  if (tid < 131072) {
    #pragma unroll
    for (int t = 0; t < 2; ++t) {
      unsigned int id = 2u * tid + t;
      int j = id & 7, lane = (id >> 3) & 63, hilo = (id >> 9) & 1;
      int mt = (id >> 10) & 3, ks = (id >> 12) & 15, chunk = (id >> 16) & 3;
      int khat = mt * 16 + (lane & 15);
      int Kl = ks * 32 + ((lane >> 4) << 3) + j;
      int z = Kl >> 7, h = chunk * 128 + (Kl & 127);
      float val = Ms[z][h * 64 + khat];
      float hi = bfhi(val);
      bits[t] = hilo ? f2bf(val - hi) : f2bf(hi);
    }
    ((unsigned int*)ws)[tid] = ((unsigned int)bits[1] << 16) | bits[0];
  } else if (tid < 196608) {
    int base = tid - 131072;
    #pragma unroll
    for (int t = 0; t < 2; ++t) {
      unsigned int id = 2u * base + t;
      int j = id & 7, lane = (id >> 3) & 63, kap = (id >> 9) & 1;
      int ht = (id >> 10) & 31, z = (id >> 15) & 3;
      int h = ht * 16 + (lane & 15);
      int kk = kap * 32 + ((lane >> 4) << 3) + j;
      bits[t] = f2h(Ms[z][h * 64 + kk]);
    }
    ((unsigned int*)(ws + 262144))[base] = ((unsigned int)bits[1] << 16) | bits[0];
  } else {
    int base = tid - 196608;
    #pragma unroll
    for (int t = 0; t < 2; ++t) {
      unsigned int id = 2u * base + t;
      int j = id & 7, lane = (id >> 3) & 63, hilo = (id >> 9) & 1;
      int mt = (id >> 10) & 3, ks = (id >> 12) & 15;
      int khat = mt * 16 + (lane & 15);
      int Kl = ks * 32 + ((lane >> 4) << 3) + j;
      float val = Bp[khat * 512 + Kl];
      float hi = bfhi(val);
      bits[t] = hilo ? f2bf(val - hi) : f2bf(hi);
    }
    ((unsigned int*)(ws + 393216))[base] = ((unsigned int)bits[1] << 16) | bits[0];
  }
}

__global__ __launch_bounds__(256, 3)
void copt_kernel(const float* __restrict__ R_U,
                 const float* __restrict__ alpha,
                 const float* __restrict__ beta,
                 const float* __restrict__ lambdas,
                 const unsigned short* __restrict__ ws,
                 float* __restrict__ out) {
  __shared__ __align__(16) float Cl[SS][KK][4];            // 4 KB fp32 C
  __shared__ __align__(16) unsigned short Cbf[2 * 512];    // 2 KB fp16 C B-frags
  __shared__ __align__(16) unsigned short Gb[16 * GST];    // 16.6 KB bf16 g / r
  __shared__ __align__(16) float Pb[TH * PST];             // 27.1 KB fwd D

  const unsigned short* AFb = ws;
  const unsigned short* AFf = ws + 262144;
  const unsigned short* AFp = ws + 393216;

  const int tid  = threadIdx.x;
  const int lane = tid & 63;
  const int wid  = tid >> 6;
  const int quad = lane >> 4;
  const int c    = lane & 15;

  const float l1 = lambdas[0], l2 = lambdas[1], l3 = lambdas[2];

  // zero Gb (cols 12..15 stay 0) and Cbf (cols 12..15 stay 0)
  for (int i = tid; i < (16 * GST) / 2; i += 256) ((unsigned int*)Gb)[i] = 0u;
  if (tid < 512) ((unsigned int*)Cbf)[tid] = 0u;
  __syncthreads();

  // ---- stage r -> Gb (bf16): Gb[3s+m][h] ----
  {
    const int s = wid, sg = blockIdx.x * SS + s;
    const float4* rp = (const float4*)(R_U + (size_t)sg * (HH * 3));
    #pragma unroll
    for (int i = 0; i < 6; ++i) {
      float4 v = rp[i * 64 + lane];
      int e = (i * 64 + lane) * 4;
      const float* pv = &v.x;
      #pragma unroll
      for (int d = 0; d < 4; ++d) {
        int ee = e + d, h = ee / 3, m = ee - 3 * h;
        Gb[(3 * s + m) * GST + h] = f2bf(pv[d]);
      }
    }
  }
  __syncthreads();

  // ---- C0 = Bp @ r via MFMA (bf16 hi/lo A, bf16 r) ----
  {
    f32x4 cacc = {0.f, 0.f, 0.f, 0.f};
    const unsigned short* gb = &Gb[c * GST + quad * 8];
    #pragma unroll 4
    for (int ks = 0; ks < 16; ++ks) {
      const unsigned short* pA = AFp + (size_t)((ks * 4 + wid) * 2) * 512 + lane * 8;
      bf16x8 ah = *(const bf16x8*)pA;
      bf16x8 al = *(const bf16x8*)(pA + 512);
      bf16x8 gg = *(const bf16x8*)(gb + ks * 32);
      cacc = __builtin_amdgcn_mfma_f32_16x16x32_bf16(ah, gg, cacc, 0, 0, 0);
      cacc = __builtin_amdgcn_mfma_f32_16x16x32_bf16(al, gg, cacc, 0, 0, 0);
    }
    if (c < 12) {
      const int s = (c * 86) >> 8, m = c - 3 * s;
      const int kr = wid * 16 + quad * 4;
      #pragma unroll
      for (int r = 0; r < 4; ++r) {
        float val = cacc[r];
        int k = kr + r;
        Cl[s][k][m] = val;
        Cbf[(k >> 5) * 512 + (((k >> 3) & 3) * 16 + c) * 8 + (k & 7)] = f2h(val);
      }
    }
  }
  __syncthreads();

  // pass1/elem ids
  const int h_l = tid & 127;
  const int sh  = tid >> 7;
  const int s0 = 2 * sh, s1 = s0 + 1;
  const int sg0 = blockIdx.x * SS + s0, sg1 = sg0 + 1;
  const float a0 = alpha[sg0], a1 = alpha[sg1];
  const float b0 = beta[sg0],  b1 = beta[sg1];
  const float* r0base = R_U + (size_t)sg0 * (HH * 3);
  const float* r1base = R_U + (size_t)sg1 * (HH * 3);

  auto elem = [&](const float acc[12], float aa, float bb,
                  const float* rp, float g[12]) {
    float P0=acc[0],P1=acc[1],P2=acc[2];
    float V0=acc[3],V1=acc[4],V2=acc[5];
    float A0=acc[6],A1=acc[7],A2=acc[8];
    float J0=acc[9],J1=acc[10],J2=acc[11];
    float v2 = V0*V0 + V1*V1 + V2*V2;
    float v  = __builtin_amdgcn_sqrtf(v2);
    float ve = v + EPSF;
    float cx0 = V1*A2 - V2*A1;
    float cx1 = V2*A0 - V0*A2;
    float cx2 = V0*A1 - V1*A0;
    float nc  = __builtin_amdgcn_sqrtf(cx0*cx0 + cx1*cx1 + cx2*cx2);
    float ve2 = ve*ve;
    float denom = ve2*ve + EPSF;
    float invd  = __builtin_amdgcn_rcpf(denom);
    float kappa = nc * invd;
    float ks  = fminf(fmaxf(kappa, 1e-4f), 1e4f);
    float lpr = bb * __logf(ks);
    float lp  = fminf(fmaxf(lpr, -10.f), 10.f);
    float tr  = aa * __expf(lp);
    float tt  = fminf(fmaxf(tr, 1e-6f), 1e6f);
    float s2  = 2.f*l2*(v - tt);
    float gtr  = (tr > 1e-6f && tr < 1e6f) ? -s2 : 0.f;
    float glpr = (lpr > -10.f && lpr < 10.f) ? gtr*tr : 0.f;
    float gk   = (kappa > 1e-4f && kappa < 1e4f)
                   ? glpr*bb*__builtin_amdgcn_rcpf(ks) : 0.f;
    float gnc  = gk * invd;
    float gden = -gk * kappa * invd;
    float gve  = 3.f * ve2 * gden;
    float gv   = s2 + gve;
    float giv  = gv * __builtin_amdgcn_rcpf(v);
    float gcs  = gnc * __builtin_amdgcn_rcpf(nc);
    float gc0 = gcs*cx0, gc1 = gcs*cx1, gc2 = gcs*cx2;
    g[0]  = 2.f*l1*(P0 - rp[0]);
    g[1]  = 2.f*l1*(P1 - rp[1]);
    g[2]  = 2.f*l1*(P2 - rp[2]);
    g[3]  = fmaf(giv, V0, A1*gc2 - A2*gc1);
    g[4]  = fmaf(giv, V1, A2*gc0 - A0*gc2);
    g[5]  = fmaf(giv, V2, A0*gc1 - A1*gc0);
    g[6]  = gc1*V2 - gc2*V1;
    g[7]  = gc2*V0 - gc0*V2;
    g[8]  = gc0*V1 - gc1*V0;
    g[9]  = 2.f*l3*J0;
    g[10] = 2.f*l3*J1;
    g[11] = 2.f*l3*J2;
  };

  for (int it = 0; it < 3; ++it) {
    f32x4 gacc = {0.f, 0.f, 0.f, 0.f};

    for (int t = 0; t < NT; ++t) {
      // ---- pass1: forward via fp16 MFMA; wave's z = wid ----
      {
        f16x8 cf0 = *(const f16x8*)&Cbf[0 * 512 + lane * 8];
        f16x8 cf1 = *(const f16x8*)&Cbf[1 * 512 + lane * 8];
        const unsigned short* afbase =
            AFf + (size_t)((wid * 32 + t * 8) * 2) * 512 + lane * 8;
        #pragma unroll 4
        for (int tau = 0; tau < 8; ++tau) {
          const unsigned short* pA = afbase + tau * 1024;
          f16x8 af0 = *(const f16x8*)pA;
          f16x8 af1 = *(const f16x8*)(pA + 512);
          f32x4 d = {0.f, 0.f, 0.f, 0.f};
          d = __builtin_amdgcn_mfma_f32_16x16x32_f16(af0, cf0, d, 0, 0, 0);
          d = __builtin_amdgcn_mfma_f32_16x16x32_f16(af1, cf1, d, 0, 0, 0);
          if (c < 12) {
            float* pp = &Pb[(tau * 16 + quad * 4) * PST + wid * 13 + c];
            pp[0 * PST] = d[0]; pp[1 * PST] = d[1];
            pp[2 * PST] = d[2]; pp[3 * PST] = d[3];
          }
        }
      }
      __syncthreads();

      // ---- elementwise gradient ----
      {
        const int h = t * TH + h_l;
        float acc0[12], acc1[12];
        #pragma unroll
        for (int z = 0; z < 4; ++z)
          #pragma unroll
          for (int m = 0; m < 3; ++m) {
            acc0[z*3+m] = Pb[h_l * PST + z * 13 + 3 * s0 + m];
            acc1[z*3+m] = Pb[h_l * PST + z * 13 + 3 * s1 + m];
          }
        float g0[12], g1[12];
        elem(acc0, a0, b0, r0base + (size_t)h * 3, g0);
        elem(acc1, a1, b1, r1base + (size_t)h * 3, g1);
        #pragma unroll
        for (int z = 0; z < 4; ++z)
          #pragma unroll
          for (int m = 0; m < 3; ++m) {
            Gb[(3*s0 + m) * GST + z*128 + h_l] = f2bf(g0[z*3 + m]);
            Gb[(3*s1 + m) * GST + z*128 + h_l] = f2bf(g1[z*3 + m]);
          }
      }
      __syncthreads();

      // ---- pass2: backward via bf16 hi/lo MFMA ----
      {
        const unsigned short* gb2 = &Gb[c * GST + quad * 8];
        #pragma unroll 4
        for (int ks = 0; ks < 16; ++ks) {
          const unsigned short* pA =
              AFb + (size_t)((((t * 16 + ks) * 4 + wid) * 2)) * 512 + lane * 8;
          bf16x8 ah = *(const bf16x8*)pA;
          bf16x8 al = *(const bf16x8*)(pA + 512);
          bf16x8 gg = *(const bf16x8*)(gb2 + ks * 32);
          gacc = __builtin_amdgcn_mfma_f32_16x16x32_bf16(ah, gg, gacc, 0, 0, 0);
          gacc = __builtin_amdgcn_mfma_f32_16x16x32_bf16(al, gg, gacc, 0, 0, 0);
        }
      }
      __syncthreads();
    }

    // ---- C update ----
    if (c < 12) {
      const int s = (c * 86) >> 8, m = c - 3 * s;
      const int kr = wid * 16 + quad * 4;
      #pragma unroll
      for (int r = 0; r < 4; ++r) {
        int k = kr + r;
        float val = Cl[s][k][m] - LR * gacc[r];
        Cl[s][k][m] = val;
        Cbf[(k >> 5) * 512 + (((k >> 3) & 3) * 16 + c) * 8 + (k & 7)] = f2h(val);
      }
    }
    __syncthreads();
  }

  const int ps = wid, psg = blockIdx.x * SS + ps;
  float* op = out + ((size_t)psg * KK + lane) * 3;
  op[0] = Cl[ps][lane][0];
  op[1] = Cl[ps][lane][1];
  op[2] = Cl[ps][lane][2];
}

extern "C" void kernel_launch(void* const* d_in, const int* in_sizes, int n_in,
                              void* d_out, int out_size, void* d_ws, size_t ws_size,
                              hipStream_t stream) {
  const float* R_U     = (const float*)d_in[0];
  const float* alpha   = (const float*)d_in[1];
  const float* beta    = (const float*)d_in[2];
  const float* lambdas = (const float*)d_in[3];
  const float* B       = (const float*)d_in[4];
  const float* Bd      = (const float*)d_in[5];
  const float* Bdd     = (const float*)d_in[6];
  const float* Bddd    = (const float*)d_in[7];
  const float* Bp      = (const float*)d_in[8];
  unsigned short* ws = (unsigned short*)d_ws;
  const int nB = in_sizes[1];   // 16384

  hipLaunchKernelGGL(prep_kernel, dim3(896), dim3(256), 0, stream,
                     B, Bd, Bdd, Bddd, Bp, ws);
  hipLaunchKernelGGL(copt_kernel, dim3(nB / SS), dim3(256), 0, stream,
                     R_U, alpha, beta, lambdas, ws, (float*)d_out);
}

// Round 4
// 411.624 us; speedup vs baseline: 5.3325x; 1.3249x over previous
//
#include <hip/hip_runtime.h>
#include <math.h>

#define EPSF 1e-8f
#define LR   1e-3f

#define HH 512
#define KK 64
#define SS 4        // samples per block
#define PbStr 36    // Pb col stride (fp16 units): 32 h + 4 pad
#define GbStr 136   // Gb col stride (fp16 units): 128 K + 8 pad
#define SLICE 4096  // per-wave pool slice (ushorts) = 8 KB
#define PbOff 0     // within slice (ushorts)
#define GbOff 1792  // within slice (ushorts); Pb ends at 1728

typedef short    bf16x8 __attribute__((ext_vector_type(8)));
typedef _Float16 f16x8  __attribute__((ext_vector_type(8)));
typedef float    f32x4  __attribute__((ext_vector_type(4)));

__device__ __forceinline__ unsigned short f2bf(float x) {
  unsigned int u = __float_as_uint(x);
  return (unsigned short)((u + 0x7fffu + ((u >> 16) & 1u)) >> 16);
}
__device__ __forceinline__ float bfhi(float x) {
  return __uint_as_float(((unsigned int)f2bf(x)) << 16);
}
__device__ __forceinline__ unsigned short f2h(float x) {
  _Float16 h = (_Float16)x;
  return *(unsigned short*)&h;
}

// ws layout (ushort units):
//  AFb @ 0      (131072): bwd A-frags, single bf16
//     f = ((chunk*4+qtr)*4+ks2)*4+mt; elem = f*512 + lane*8 + j
//     khat=mt*16+(lane&15); kq=(lane>>4)*8+j; h=chunk*128+qtr*32+kq; val=Ms[ks2][h*64+khat]
//  AFf @ 131072 (131072): fwd A-frags fp16
//     f=(z*32+ht)*2+kap; elem=f*512+lane*8+j
//     h=ht*16+(lane&15); kk=kap*32+(lane>>4)*8+j; val=Ms[z][h*64+kk]
//  AFp @ 262144 (65536): C0 A-frags bf16 hi/lo (Bp)
//     f=(ks*4+mt)*2+hilo; elem=f*512+lane*8+j
//     khat=mt*16+(lane&15); Kl=ks*32+(lane>>4)*8+j; val=Bp[khat*512+Kl]
__global__ void prep_kernel(const float* __restrict__ B,
                            const float* __restrict__ Bd,
                            const float* __restrict__ Bdd,
                            const float* __restrict__ Bddd,
                            const float* __restrict__ Bp,
                            unsigned short* __restrict__ ws) {
  int tid = blockIdx.x * 256 + threadIdx.x;   // 640 * 256 = 163840
  const float* Ms[4] = {B, Bd, Bdd, Bddd};
  unsigned short bits[2];
  if (tid < 65536) {
    #pragma unroll
    for (int t = 0; t < 2; ++t) {
      unsigned int id = 2u * tid + t;
      int j = id & 7, lane = (id >> 3) & 63;
      int mt = (id >> 9) & 3, ks2 = (id >> 11) & 3;
      int qtr = (id >> 13) & 3, chunk = (id >> 15) & 3;
      int khat = mt * 16 + (lane & 15);
      int kq = ((lane >> 4) << 3) + j;
      int h = chunk * 128 + qtr * 32 + kq;
      bits[t] = f2bf(Ms[ks2][h * 64 + khat]);
    }
    ((unsigned int*)ws)[tid] = ((unsigned int)bits[1] << 16) | bits[0];
  } else if (tid < 131072) {
    int base = tid - 65536;
    #pragma unroll
    for (int t = 0; t < 2; ++t) {
      unsigned int id = 2u * base + t;
      int j = id & 7, lane = (id >> 3) & 63, kap = (id >> 9) & 1;
      int ht = (id >> 10) & 31, z = (id >> 15) & 3;
      int h = ht * 16 + (lane & 15);
      int kk = kap * 32 + ((lane >> 4) << 3) + j;
      bits[t] = f2h(Ms[z][h * 64 + kk]);
    }
    ((unsigned int*)(ws + 131072))[base] = ((unsigned int)bits[1] << 16) | bits[0];
  } else {
    int base = tid - 131072;
    #pragma unroll
    for (int t = 0; t < 2; ++t) {
      unsigned int id = 2u * base + t;
      int j = id & 7, lane = (id >> 3) & 63, hilo = (id >> 9) & 1;
      int mt = (id >> 10) & 3, ks = (id >> 12) & 15;
      int khat = mt * 16 + (lane & 15);
      int Kl = ks * 32 + ((lane >> 4) << 3) + j;
      float val = Bp[khat * 512 + Kl];
      float hi = bfhi(val);
      bits[t] = hilo ? f2bf(val - hi) : f2bf(hi);
    }
    ((unsigned int*)(ws + 262144))[base] = ((unsigned int)bits[1] << 16) | bits[0];
  }
}

__global__ __launch_bounds__(256, 4)
void copt_kernel(const float* __restrict__ R_U,
                 const float* __restrict__ alpha,
                 const float* __restrict__ beta,
                 const float* __restrict__ lambdas,
                 const unsigned short* __restrict__ ws,
                 float* __restrict__ out) {
  __shared__ __align__(16) float Cl[SS][KK][4];           // 4 KB fp32 C
  __shared__ __align__(16) unsigned short Cbf[2 * 512];   // 2 KB fp16 C B-frags
  __shared__ __align__(16) unsigned short pool[4 * SLICE];// 32 KB: per-wave Pb+Gb, aliased Rb & r-stage

  const unsigned short* AFb = ws;
  const unsigned short* AFf = ws + 131072;
  const unsigned short* AFp = ws + 262144;

  const int tid  = threadIdx.x;
  const int lane = tid & 63;
  const int wid  = tid >> 6;
  const int quad = lane >> 4;
  const int c    = lane & 15;

  const float l1 = lambdas[0], l2 = lambdas[1], l3 = lambdas[2];
  const int bg = blockIdx.x * SS;

  if (tid < 512) ((unsigned int*)Cbf)[tid] = 0u;   // cols 12..15 stay 0 forever

  // ---- stage r -> pool (bf16): [col=3s+m][h], stride 520 (s=wid) ----
  {
    const int s = wid, sg = bg + s;
    const float4* rp = (const float4*)(R_U + (size_t)sg * (HH * 3));
    #pragma unroll
    for (int i = 0; i < 6; ++i) {
      float4 v = rp[i * 64 + lane];
      int e = (i * 64 + lane) * 4;
      const float* pv = &v.x;
      #pragma unroll
      for (int d = 0; d < 4; ++d) {
        int ee = e + d, h = ee / 3, m = ee - 3 * h;
        pool[(3 * s + m) * 520 + h] = f2bf(pv[d]);
      }
    }
  }
  __syncthreads();

  // ---- C0 = Bp @ r via MFMA (bf16 hi/lo A, bf16 r); this wave: mt = wid ----
  {
    f32x4 cacc = {0.f, 0.f, 0.f, 0.f};
    const unsigned short* gb = &pool[c * 520 + quad * 8];
    #pragma unroll 4
    for (int ks = 0; ks < 16; ++ks) {
      const unsigned short* pA = AFp + (size_t)((ks * 4 + wid) * 2) * 512 + lane * 8;
      bf16x8 ah = *(const bf16x8*)pA;
      bf16x8 al = *(const bf16x8*)(pA + 512);
      bf16x8 gg = *(const bf16x8*)(gb + ks * 32);
      cacc = __builtin_amdgcn_mfma_f32_16x16x32_bf16(ah, gg, cacc, 0, 0, 0);
      cacc = __builtin_amdgcn_mfma_f32_16x16x32_bf16(al, gg, cacc, 0, 0, 0);
    }
    if (c < 12) {
      const int s = (c * 86) >> 8, m = c - 3 * s;
      const int kr = wid * 16 + quad * 4;
      #pragma unroll
      for (int r = 0; r < 4; ++r) {
        float val = cacc[r];
        int k = kr + r;
        Cl[s][k][m] = val;
        Cbf[(k >> 5) * 512 + (((k >> 3) & 3) * 16 + c) * 8 + (k & 7)] = f2h(val);
      }
    }
  }
  __syncthreads();

  // elem thread ids: h = hq (lane&31), sample-pair by lane>>5
  const int hq = lane & 31;
  const int es0 = 2 * (lane >> 5), es1 = es0 + 1;
  const float ea0 = alpha[bg + es0], ea1 = alpha[bg + es1];
  const float eb0 = beta[bg + es0],  eb1 = beta[bg + es1];
  const float* er0 = R_U + (size_t)(bg + es0) * (HH * 3);
  const float* er1 = R_U + (size_t)(bg + es1) * (HH * 3);

  unsigned short* Pb = pool + wid * SLICE + PbOff;   // [48 cols][36]
  unsigned short* Gb = pool + wid * SLICE + GbOff;   // [16 cols][136]

  auto elem = [&](const float acc[12], float aa, float bb,
                  const float* rp, float g[12]) {
    float P0=acc[0],P1=acc[1],P2=acc[2];
    float V0=acc[3],V1=acc[4],V2=acc[5];
    float A0=acc[6],A1=acc[7],A2=acc[8];
    float J0=acc[9],J1=acc[10],J2=acc[11];
    float v2 = V0*V0 + V1*V1 + V2*V2;
    float v  = __builtin_amdgcn_sqrtf(v2);
    float ve = v + EPSF;
    float cx0 = V1*A2 - V2*A1;
    float cx1 = V2*A0 - V0*A2;
    float cx2 = V0*A1 - V1*A0;
    float nc  = __builtin_amdgcn_sqrtf(cx0*cx0 + cx1*cx1 + cx2*cx2);
    float ve2 = ve*ve;
    float denom = ve2*ve + EPSF;
    float invd  = __builtin_amdgcn_rcpf(denom);
    float kappa = nc * invd;
    float ks  = fminf(fmaxf(kappa, 1e-4f), 1e4f);
    float lpr = bb * __logf(ks);
    float lp  = fminf(fmaxf(lpr, -10.f), 10.f);
    float tr  = aa * __expf(lp);
    float tt  = fminf(fmaxf(tr, 1e-6f), 1e6f);
    float s2  = 2.f*l2*(v - tt);
    float gtr  = (tr > 1e-6f && tr < 1e6f) ? -s2 : 0.f;
    float glpr = (lpr > -10.f && lpr < 10.f) ? gtr*tr : 0.f;
    float gk   = (kappa > 1e-4f && kappa < 1e4f)
                   ? glpr*bb*__builtin_amdgcn_rcpf(ks) : 0.f;
    float gnc  = gk * invd;
    float gden = -gk * kappa * invd;
    float gve  = 3.f * ve2 * gden;
    float gv   = s2 + gve;
    float giv  = gv * __builtin_amdgcn_rcpf(v);
    float gcs  = gnc * __builtin_amdgcn_rcpf(nc);
    float gc0 = gcs*cx0, gc1 = gcs*cx1, gc2 = gcs*cx2;
    g[0]  = 2.f*l1*(P0 - rp[0]);
    g[1]  = 2.f*l1*(P1 - rp[1]);
    g[2]  = 2.f*l1*(P2 - rp[2]);
    g[3]  = fmaf(giv, V0, A1*gc2 - A2*gc1);
    g[4]  = fmaf(giv, V1, A2*gc0 - A0*gc2);
    g[5]  = fmaf(giv, V2, A0*gc1 - A1*gc0);
    g[6]  = gc1*V2 - gc2*V1;
    g[7]  = gc2*V0 - gc0*V2;
    g[8]  = gc0*V1 - gc1*V0;
    g[9]  = 2.f*l3*J0;
    g[10] = 2.f*l3*J1;
    g[11] = 2.f*l3*J2;
  };

  for (int it = 0; it < 3; ++it) {
    f32x4 gacc[4];
    #pragma unroll
    for (int mt = 0; mt < 4; ++mt) gacc[mt] = (f32x4){0.f, 0.f, 0.f, 0.f};

    // fwd B-frags (C fp16) for this iteration
    f16x8 cf0 = *(const f16x8*)&Cbf[lane * 8];
    f16x8 cf1 = *(const f16x8*)&Cbf[512 + lane * 8];

    for (int q = 0; q < 4; ++q) {
      // ---- forward: 8 MFMA-tiles (2 ht x 4 z), wave-local ----
      #pragma unroll
      for (int ht = 0; ht < 2; ++ht) {
        const int htg = wid * 8 + q * 2 + ht;
        #pragma unroll
        for (int z = 0; z < 4; ++z) {
          const unsigned short* pA =
              AFf + (size_t)((z * 32 + htg) * 2) * 512 + lane * 8;
          f16x8 af0 = *(const f16x8*)pA;
          f16x8 af1 = *(const f16x8*)(pA + 512);
          f32x4 d = {0.f, 0.f, 0.f, 0.f};
          d = __builtin_amdgcn_mfma_f32_16x16x32_f16(af0, cf0, d, 0, 0, 0);
          d = __builtin_amdgcn_mfma_f32_16x16x32_f16(af1, cf1, d, 0, 0, 0);
          if (c < 12) {
            uint2 pk;
            pk.x = (unsigned int)f2h(d[0]) | ((unsigned int)f2h(d[1]) << 16);
            pk.y = (unsigned int)f2h(d[2]) | ((unsigned int)f2h(d[3]) << 16);
            *(uint2*)&Pb[(z * 12 + c) * PbStr + ht * 16 + quad * 4] = pk;
          }
        }
      }

      // ---- elementwise: this wave's 32 h, thread = (h, sample-pair) ----
      {
        float acc0[12], acc1[12];
        #pragma unroll
        for (int z = 0; z < 4; ++z)
          #pragma unroll
          for (int m = 0; m < 3; ++m) {
            acc0[z*3+m] = (float)*(const _Float16*)&Pb[(z*12 + 3*es0 + m) * PbStr + hq];
            acc1[z*3+m] = (float)*(const _Float16*)&Pb[(z*12 + 3*es1 + m) * PbStr + hq];
          }
        const int hg = wid * 128 + q * 32 + hq;
        float g0[12], g1[12];
        elem(acc0, ea0, eb0, er0 + (size_t)hg * 3, g0);
        elem(acc1, ea1, eb1, er1 + (size_t)hg * 3, g1);
        #pragma unroll
        for (int z = 0; z < 4; ++z)
          #pragma unroll
          for (int m = 0; m < 3; ++m) {
            Gb[(3*es0 + m) * GbStr + z*32 + hq] = f2bf(g0[z*3 + m]);
            Gb[(3*es1 + m) * GbStr + z*32 + hq] = f2bf(g1[z*3 + m]);
          }
      }

      // ---- backward partial: all 4 m-tiles over this wave's K-slice ----
      #pragma unroll
      for (int ks2 = 0; ks2 < 4; ++ks2) {
        bf16x8 gg = *(const bf16x8*)&Gb[c * GbStr + ks2 * 32 + quad * 8];
        #pragma unroll
        for (int mt = 0; mt < 4; ++mt) {
          const unsigned short* pA =
              AFb + (size_t)(((wid * 4 + q) * 4 + ks2) * 4 + mt) * 512 + lane * 8;
          bf16x8 a = *(const bf16x8*)pA;
          gacc[mt] = __builtin_amdgcn_mfma_f32_16x16x32_bf16(a, gg, gacc[mt], 0, 0, 0);
        }
      }
    }

    // ---- dump partials (own slice), reduce, update C ----
    {
      char* poolB = (char*)pool;
      #pragma unroll
      for (int mt = 0; mt < 4; ++mt)
        *(f32x4*)(poolB + wid * 8192 + mt * 1024 + lane * 16) = gacc[mt];
    }
    __syncthreads();
    {
      const char* poolB = (const char*)pool;
      f32x4 tot = {0.f, 0.f, 0.f, 0.f};
      #pragma unroll
      for (int v = 0; v < 4; ++v)
        tot += *(const f32x4*)(poolB + v * 8192 + wid * 1024 + lane * 16);
      if (c < 12) {
        const int s = (c * 86) >> 8, m = c - 3 * s;
        const int kr = wid * 16 + quad * 4;
        #pragma unroll
        for (int r = 0; r < 4; ++r) {
          int k = kr + r;
          float val = Cl[s][k][m] - LR * tot[r];
          Cl[s][k][m] = val;
          Cbf[(k >> 5) * 512 + (((k >> 3) & 3) * 16 + c) * 8 + (k & 7)] = f2h(val);
        }
      }
    }
    __syncthreads();
  }

  const int ps = wid, psg = bg + ps;
  float* op = out + ((size_t)psg * KK + lane) * 3;
  op[0] = Cl[ps][lane][0];
  op[1] = Cl[ps][lane][1];
  op[2] = Cl[ps][lane][2];
}

extern "C" void kernel_launch(void* const* d_in, const int* in_sizes, int n_in,
                              void* d_out, int out_size, void* d_ws, size_t ws_size,
                              hipStream_t stream) {
  const float* R_U     = (const float*)d_in[0];
  const float* alpha   = (const float*)d_in[1];
  const float* beta    = (const float*)d_in[2];
  const float* lambdas = (const float*)d_in[3];
  const float* B       = (const float*)d_in[4];
  const float* Bd      = (const float*)d_in[5];
  const float* Bdd     = (const float*)d_in[6];
  const float* Bddd    = (const float*)d_in[7];
  const float* Bp      = (const float*)d_in[8];
  unsigned short* ws = (unsigned short*)d_ws;
  const int nB = in_sizes[1];   // 16384

  hipLaunchKernelGGL(prep_kernel, dim3(640), dim3(256), 0, stream,
                     B, Bd, Bdd, Bddd, Bp, ws);
  hipLaunchKernelGGL(copt_kernel, dim3(nB / SS), dim3(256), 0, stream,
                     R_U, alpha, beta, lambdas, ws, (float*)d_out);
}